// Round 5
// baseline (292.300 us; speedup 1.0000x reference)
//
#include <hip/hip_runtime.h>
#include <hip/hip_bf16.h>

#define N_NODES 50000
#define N_EDGES 1600000
#define HEADS 8
#define HFD 16
#define CH 128      // channels

// bucketing: bucket = dst>>7 (128 dst nodes per bucket)
#define PART 128
#define NB 391              // ceil(50000/128)
#define BCAP 5120           // edge capacity per bucket (mean 4096, +16 sigma)
#define PA_T 512
#define PA_CHUNK 6400       // edges per pass-A block
#define PA_BLOCKS 250       // 250*6400 = 1.6M

typedef __bf16 bf16x8 __attribute__((ext_vector_type(8)));
typedef __bf16 bf16x4 __attribute__((ext_vector_type(4)));
typedef float f32x4 __attribute__((ext_vector_type(4)));

__device__ __forceinline__ float bf_lo(unsigned u) { return __uint_as_float(u << 16); }
__device__ __forceinline__ float bf_hi(unsigned u) { return __uint_as_float(u & 0xffff0000u); }

// ---------------------------------------------------------------------------
// Split f32 -> bf16 hi/lo pair (x ~= hi+lo), 4 elems/thread. Used for W only.
// ---------------------------------------------------------------------------
__global__ __launch_bounds__(256) void k_splitw(const float* __restrict__ x,
                                                __bf16* __restrict__ hi,
                                                __bf16* __restrict__ lo,
                                                int n4) {
  int t = blockIdx.x * 256 + threadIdx.x;
  if (t >= n4) return;
  f32x4 v = ((const f32x4*)x)[t];
  bf16x4 h, l;
#pragma unroll
  for (int i = 0; i < 4; ++i) {
    __bf16 hb = (__bf16)v[i];
    h[i] = hb;
    l[i] = (__bf16)(v[i] - (float)hb);
  }
  ((bf16x4*)hi)[t] = h;
  ((bf16x4*)lo)[t] = l;
}

// ---------------------------------------------------------------------------
// emb = X @ W^T via split-bf16 MFMA (fp32-accurate; W pre-split, X split
// in-register), fused per-(node,head) logits via shuffle-reduce, bf16 emb out.
// One wave per 16x16 tile; ctile == head. C/D: col=lane&15, row=(lane>>4)*4+r.
// ---------------------------------------------------------------------------
__global__ __launch_bounds__(64) void k_emb(const float* __restrict__ X,
                                            const __bf16* __restrict__ Whi,
                                            const __bf16* __restrict__ Wlo,
                                            const float* __restrict__ aL,
                                            const float* __restrict__ aR,
                                            __bf16* __restrict__ embb,
                                            float* __restrict__ leftp,
                                            float* __restrict__ rightp) {
  int wave = blockIdx.x;
  int ntile = wave >> 3;
  int h = wave & 7;          // ctile == head
  int lane = threadIdx.x;
  int c = lane & 15, quad = lane >> 4;
  const float* xp = X + (size_t)(ntile * 16 + c) * CH + quad * 8;
  const __bf16* wp = Whi + (size_t)(h * 16 + c) * CH + quad * 8;
  const __bf16* wlp = Wlo + (size_t)(h * 16 + c) * CH + quad * 8;
  f32x4 acc = {0.f, 0.f, 0.f, 0.f};
#pragma unroll
  for (int ks = 0; ks < 4; ++ks) {
    float4 x0 = *(const float4*)(xp + ks * 32);
    float4 x1 = *(const float4*)(xp + ks * 32 + 4);
    bf16x8 wh = *(const bf16x8*)(wp + ks * 32);
    bf16x8 wl = *(const bf16x8*)(wlp + ks * 32);
    float xv[8] = {x0.x, x0.y, x0.z, x0.w, x1.x, x1.y, x1.z, x1.w};
    bf16x8 xh, xl;
#pragma unroll
    for (int j = 0; j < 8; ++j) {
      __bf16 hb = (__bf16)xv[j];
      xh[j] = hb;
      xl[j] = (__bf16)(xv[j] - (float)hb);
    }
    acc = __builtin_amdgcn_mfma_f32_16x16x32_bf16(xl, wh, acc, 0, 0, 0);
    acc = __builtin_amdgcn_mfma_f32_16x16x32_bf16(xh, wl, acc, 0, 0, 0);
    acc = __builtin_amdgcn_mfma_f32_16x16x32_bf16(xh, wh, acc, 0, 0, 0);
  }
  float aLv = aL[c * HEADS + h];
  float aRv = aR[c * HEADS + h];
#pragma unroll
  for (int r = 0; r < 4; ++r) {
    int node = ntile * 16 + quad * 4 + r;
    float v = acc[r];
    embb[(size_t)node * CH + h * HFD + c] = (__bf16)v;
    float sl = v * aLv, sr = v * aRv;
#pragma unroll
    for (int m = 1; m < 16; m <<= 1) {
      sl += __shfl_xor(sl, m);
      sr += __shfl_xor(sr, m);
    }
    if (c == 0) {
      leftp[node * HEADS + h] = sl;
      rightp[node * HEADS + h] = sr;
    }
  }
}

// ---------------------------------------------------------------------------
// Pass A: bucket edges by dst>>7. Edges packed to 4 B:
//   p = (bucket:9 << 23) | (dstloc:7 << 16) | (src:16)   [src < 65536]
// Each block LDS-sorts its 6400-edge chunk by bucket, reserves global space
// with ONE returning atomic per (block,bucket), then writes run-contiguous
// 4 B runs (mean 16 edges) -> cache lines get filled, no write shredding.
// ---------------------------------------------------------------------------
__global__ __launch_bounds__(PA_T) void k_bucket(const int* __restrict__ ei,
                                                 int* __restrict__ bucket_cnt,
                                                 unsigned* __restrict__ ebuf) {
  __shared__ unsigned sp[PA_CHUNK];   // 25.6 KB sorted edges
  __shared__ int hist[NB];
  __shared__ int lcur[NB];
  __shared__ int wbase[NB];
  __shared__ int scan[PA_T];
  int t = threadIdx.x;
  int base = blockIdx.x * PA_CHUNK;
  for (int i = t; i < NB; i += PA_T) hist[i] = 0;
  __syncthreads();
  // pass 1: histogram of buckets
  for (int e = t; e < PA_CHUNK; e += PA_T) {
    int dst = ei[N_EDGES + base + e];
    atomicAdd(&hist[dst >> 7], 1);
  }
  __syncthreads();
  // exclusive scan over NB buckets (padded Hillis-Steele over 512)
  scan[t] = (t < NB) ? hist[t] : 0;
  __syncthreads();
  int val = scan[t];
  for (int d = 1; d < PA_T; d <<= 1) {
    int o = (t >= d) ? scan[t - d] : 0;
    __syncthreads();
    val += o;
    scan[t] = val;
    __syncthreads();
  }
  if (t < NB) {
    int hv = hist[t];
    int lstart = scan[t] - hv;   // exclusive prefix
    lcur[t] = lstart;
    int prior = hv ? atomicAdd(&bucket_cnt[t], hv) : 0;
    wbase[t] = t * BCAP + prior - lstart;
  }
  __syncthreads();
  // pass 2: place packed edges into LDS in bucket-sorted order
  for (int e = t; e < PA_CHUNK; e += PA_T) {
    int src = ei[base + e];
    int dst = ei[N_EDGES + base + e];
    unsigned p = ((unsigned)(dst >> 7) << 23) | ((unsigned)(dst & 127) << 16) |
                 (unsigned)src;
    int pos = atomicAdd(&lcur[dst >> 7], 1);
    sp[pos] = p;
  }
  __syncthreads();
  // pass 3: run-contiguous global writes
  for (int i = t; i < PA_CHUNK; i += PA_T) {
    unsigned p = sp[i];
    int b = p >> 23;
    int slot = wbase[b] + i;
    if (slot < (b + 1) * BCAP) ebuf[slot] = p;  // capacity guard (never fires)
  }
}

// ---------------------------------------------------------------------------
// Pass B: per bucket, LDS histogram over its 128 dsts -> scan -> rowptr/deg
// -> LDS-cursor scatter of u16 src ids into the bucket's csr window.
// ---------------------------------------------------------------------------
__global__ __launch_bounds__(512) void k_csr(const int* __restrict__ bucket_cnt,
                                             const unsigned* __restrict__ ebuf,
                                             int* __restrict__ rowptr,
                                             int* __restrict__ deg,
                                             unsigned short* __restrict__ csr) {
  __shared__ int hist[PART];
  __shared__ int pfx[PART];
  __shared__ int cur[PART];
  int b = blockIdx.x, t = threadIdx.x;
  int cnt = bucket_cnt[b];
  if (cnt > BCAP) cnt = BCAP;
  int ebase = b * BCAP;
  if (t < PART) hist[t] = 0;
  __syncthreads();
  for (int e = t; e < cnt; e += 512)
    atomicAdd(&hist[(ebuf[ebase + e] >> 16) & 127], 1);
  __syncthreads();
  if (t < PART) pfx[t] = hist[t];
  __syncthreads();
  for (int d = 1; d < PART; d <<= 1) {
    int v = 0;
    if (t < PART) { v = pfx[t]; if (t >= d) v += pfx[t - d]; }
    __syncthreads();
    if (t < PART) pfx[t] = v;
    __syncthreads();
  }
  if (t < PART) {
    int excl = pfx[t] - hist[t];
    cur[t] = ebase + excl;
    int dst = b * PART + t;
    if (dst < N_NODES) {
      rowptr[dst] = ebase + excl;
      deg[dst] = hist[t];
    }
  }
  __syncthreads();
  for (int e = t; e < cnt; e += 512) {
    unsigned p = ebuf[ebase + e];
    int pos = atomicAdd(&cur[(p >> 16) & 127], 1);
    csr[pos] = (unsigned short)(p & 0xffffu);
  }
}

// ---------------------------------------------------------------------------
// Pull-aggregate, 8-wide unrolled: 8 independent embb/leftp gathers in
// flight per wave (tail masked via index clamp + w=0). Lane l owns channels
// 2l,2l+1; head h=l>>3. out = (sum w*emb[src]) / (sum w) + bias.
// ---------------------------------------------------------------------------
__global__ __launch_bounds__(256) void k_aggr(const int* __restrict__ rowptr,
                                              const int* __restrict__ deg,
                                              const unsigned short* __restrict__ csr,
                                              const __bf16* __restrict__ embb,
                                              const float* __restrict__ leftp,
                                              const float* __restrict__ rightp,
                                              const float* __restrict__ bias,
                                              float* __restrict__ out) {
  int dst = blockIdx.x * 4 + (threadIdx.x >> 6);
  int lane = threadIdx.x & 63;
  int h = lane >> 3;
  int beg = __builtin_amdgcn_readfirstlane(rowptr[dst]);
  int end = beg + __builtin_amdgcn_readfirstlane(deg[dst]);
  float r = rightp[dst * HEADS + h];
  float ax = 0.f, ay = 0.f, dsum = 0.f;
  for (int e = beg; e < end; e += 8) {
    int s[8];
#pragma unroll
    for (int j = 0; j < 8; ++j) {
      int idx = e + j;
      s[j] = __builtin_amdgcn_readfirstlane((int)csr[idx < end ? idx : beg]);
    }
    unsigned u[8];
    float l[8];
#pragma unroll
    for (int j = 0; j < 8; ++j) {
      u[j] = ((const unsigned*)(embb + (size_t)s[j] * CH))[lane];
      l[j] = leftp[s[j] * HEADS + h];
    }
#pragma unroll
    for (int j = 0; j < 8; ++j) {
      float x = l[j] + r;
      x = (x >= 0.f) ? x : 0.2f * x;
      float w = ((e + j) < end) ? __expf(x) : 0.f;
      ax += w * bf_lo(u[j]);
      ay += w * bf_hi(u[j]);
      dsum += w;
    }
  }
  float inv = (dsum > 0.f) ? 1.0f / dsum : 0.f;
  float2 bv = ((const float2*)bias)[lane];
  float2 o = {ax * inv + bv.x, ay * inv + bv.y};
  ((float2*)(out + (size_t)dst * CH))[lane] = o;
}

extern "C" void kernel_launch(void* const* d_in, const int* in_sizes, int n_in,
                              void* d_out, int out_size, void* d_ws, size_t ws_size,
                              hipStream_t stream) {
  const float* X = (const float*)d_in[0];
  const int* ei = (const int*)d_in[1];
  const float* W = (const float*)d_in[2];
  const float* al = (const float*)d_in[3];
  const float* ar = (const float*)d_in[4];
  const float* bias = (const float*)d_in[5];
  float* out = (float*)d_out;

  // workspace layout (~28.6 MB), all segments 16 B-aligned
  unsigned* ebuf = (unsigned*)d_ws;                       // NB*BCAP u32 (8.0 MB)
  unsigned short* csr = (unsigned short*)(ebuf + (size_t)NB * BCAP);  // NB*BCAP u16 (4.0 MB)
  int* rowptr = (int*)(csr + (size_t)NB * BCAP);          // N int
  int* deg = rowptr + N_NODES;                            // N int
  int* bucket_cnt = deg + N_NODES;                        // NB int (pad 400)
  float* leftp = (float*)(bucket_cnt + 400);              // N*8 f32
  float* rightp = leftp + (size_t)N_NODES * HEADS;        // N*8 f32
  __bf16* embb = (__bf16*)(rightp + (size_t)N_NODES * HEADS);  // N*128 bf16 (12.8 MB)
  __bf16* Whi = embb + (size_t)N_NODES * CH;              // 16K bf16
  __bf16* Wlo = Whi + CH * CH;                            // 16K bf16

  hipMemsetAsync(bucket_cnt, 0, NB * sizeof(int), stream);

  k_splitw<<<(CH * CH / 4 + 255) / 256, 256, 0, stream>>>(W, Whi, Wlo, CH * CH / 4);
  k_emb<<<(N_NODES / 16) * 8, 64, 0, stream>>>(X, Whi, Wlo, al, ar, embb, leftp, rightp);
  k_bucket<<<PA_BLOCKS, PA_T, 0, stream>>>(ei, bucket_cnt, ebuf);
  k_csr<<<NB, 512, 0, stream>>>(bucket_cnt, ebuf, rowptr, deg, csr);
  k_aggr<<<N_NODES / 4, 256, 0, stream>>>(rowptr, deg, csr, embb, leftp, rightp, bias, out);
}

// Round 6
// 234.687 us; speedup vs baseline: 1.2455x; 1.2455x over previous
//
#include <hip/hip_runtime.h>
#include <hip/hip_bf16.h>

#define N_NODES 50000
#define N_EDGES 1600000
#define HEADS 8
#define HFD 16
#define CH 128      // channels

// bucketing: bucket = dst>>7 (128 dst nodes per bucket)
#define PART 128
#define NB 391              // ceil(50000/128)
#define BCAP 5120           // edge capacity per bucket (mean 4096, +16 sigma)
#define PA_T 512
#define PA_CHUNK 6400       // edges per pass-A block
#define PA_PER 13           // 512*13 = 6656 >= 6400
#define PA_BLOCKS 250       // 250*6400 = 1.6M

typedef __bf16 bf16x8 __attribute__((ext_vector_type(8)));
typedef __bf16 bf16x4 __attribute__((ext_vector_type(4)));
typedef float f32x4 __attribute__((ext_vector_type(4)));

__device__ __forceinline__ float bf_lo(unsigned u) { return __uint_as_float(u << 16); }
__device__ __forceinline__ float bf_hi(unsigned u) { return __uint_as_float(u & 0xffff0000u); }

// ---------------------------------------------------------------------------
// Split f32 -> bf16 hi/lo pair (x ~= hi+lo), 4 elems/thread. Used for W only.
// ---------------------------------------------------------------------------
__global__ __launch_bounds__(256) void k_splitw(const float* __restrict__ x,
                                                __bf16* __restrict__ hi,
                                                __bf16* __restrict__ lo,
                                                int n4) {
  int t = blockIdx.x * 256 + threadIdx.x;
  if (t >= n4) return;
  f32x4 v = ((const f32x4*)x)[t];
  bf16x4 h, l;
#pragma unroll
  for (int i = 0; i < 4; ++i) {
    __bf16 hb = (__bf16)v[i];
    h[i] = hb;
    l[i] = (__bf16)(v[i] - (float)hb);
  }
  ((bf16x4*)hi)[t] = h;
  ((bf16x4*)lo)[t] = l;
}

// ---------------------------------------------------------------------------
// emb = X @ W^T via split-bf16 MFMA. One wave per 16-node row block; the wave
// loads+splits its A-fragments ONCE and loops over all 8 head tiles (8x less
// X traffic than tile-per-wave). Fused logits via shuffle-reduce; bf16 emb.
// C/D: col=lane&15, row=(lane>>4)*4+r (HW-verified, passed r2-r5).
// ---------------------------------------------------------------------------
__global__ __launch_bounds__(64) void k_emb(const float* __restrict__ X,
                                            const __bf16* __restrict__ Whi,
                                            const __bf16* __restrict__ Wlo,
                                            const float* __restrict__ aL,
                                            const float* __restrict__ aR,
                                            __bf16* __restrict__ embb,
                                            float* __restrict__ leftp,
                                            float* __restrict__ rightp) {
  int ntile = blockIdx.x;
  int lane = threadIdx.x;
  int c = lane & 15, quad = lane >> 4;
  const float* xp = X + (size_t)(ntile * 16 + c) * CH + quad * 8;
  bf16x8 xh[4], xl[4];
#pragma unroll
  for (int ks = 0; ks < 4; ++ks) {
    float4 x0 = *(const float4*)(xp + ks * 32);
    float4 x1 = *(const float4*)(xp + ks * 32 + 4);
    float xv[8] = {x0.x, x0.y, x0.z, x0.w, x1.x, x1.y, x1.z, x1.w};
#pragma unroll
    for (int j = 0; j < 8; ++j) {
      __bf16 hb = (__bf16)xv[j];
      xh[ks][j] = hb;
      xl[ks][j] = (__bf16)(xv[j] - (float)hb);
    }
  }
#pragma unroll
  for (int h = 0; h < HEADS; ++h) {
    const __bf16* wp = Whi + (size_t)(h * 16 + c) * CH + quad * 8;
    const __bf16* wlp = Wlo + (size_t)(h * 16 + c) * CH + quad * 8;
    f32x4 acc = {0.f, 0.f, 0.f, 0.f};
#pragma unroll
    for (int ks = 0; ks < 4; ++ks) {
      bf16x8 wh = *(const bf16x8*)(wp + ks * 32);
      bf16x8 wl = *(const bf16x8*)(wlp + ks * 32);
      acc = __builtin_amdgcn_mfma_f32_16x16x32_bf16(xl[ks], wh, acc, 0, 0, 0);
      acc = __builtin_amdgcn_mfma_f32_16x16x32_bf16(xh[ks], wl, acc, 0, 0, 0);
      acc = __builtin_amdgcn_mfma_f32_16x16x32_bf16(xh[ks], wh, acc, 0, 0, 0);
    }
    float aLv = aL[c * HEADS + h];
    float aRv = aR[c * HEADS + h];
#pragma unroll
    for (int r = 0; r < 4; ++r) {
      int node = ntile * 16 + quad * 4 + r;
      float v = acc[r];
      embb[(size_t)node * CH + h * HFD + c] = (__bf16)v;
      float sl = v * aLv, sr = v * aRv;
#pragma unroll
      for (int mm = 1; mm < 16; mm <<= 1) {
        sl += __shfl_xor(sl, mm);
        sr += __shfl_xor(sr, mm);
      }
      if (c == 0) {
        leftp[node * HEADS + h] = sl;
        rightp[node * HEADS + h] = sr;
      }
    }
  }
}

// ---------------------------------------------------------------------------
// Pass A: bucket edges by dst>>7. Packed 4 B edges held in REGISTERS through
// hist -> scan -> LDS bucket-sort (single ei read), then run-contiguous
// global writes into per-bucket windows (one reserving atomic per
// block,bucket pair).  p = (bucket:9 <<23) | (dstloc:7 <<16) | (src:16).
// ---------------------------------------------------------------------------
__global__ __launch_bounds__(PA_T) void k_bucket(const int* __restrict__ ei,
                                                 int* __restrict__ bucket_cnt,
                                                 unsigned* __restrict__ ebuf) {
  __shared__ unsigned sp[PA_CHUNK];   // 25.6 KB sorted edges
  __shared__ int hist[NB];
  __shared__ int lcur[NB];
  __shared__ int wbase[NB];
  __shared__ int scn[PA_T];
  int t = threadIdx.x;
  int base = blockIdx.x * PA_CHUNK;
  for (int i = t; i < NB; i += PA_T) hist[i] = 0;
  __syncthreads();
  unsigned pk[PA_PER];
#pragma unroll
  for (int i = 0; i < PA_PER; ++i) {
    int e = t + i * PA_T;
    pk[i] = 0xffffffffu;
    if (e < PA_CHUNK) {
      int src = ei[base + e];
      int dst = ei[N_EDGES + base + e];
      pk[i] = ((unsigned)(dst >> 7) << 23) | ((unsigned)(dst & 127) << 16) |
              (unsigned)src;
      atomicAdd(&hist[dst >> 7], 1);
    }
  }
  __syncthreads();
  // exclusive scan over NB buckets (padded Hillis-Steele over 512)
  scn[t] = (t < NB) ? hist[t] : 0;
  __syncthreads();
  int val = scn[t];
  for (int d = 1; d < PA_T; d <<= 1) {
    int o = (t >= d) ? scn[t - d] : 0;
    __syncthreads();
    val += o;
    scn[t] = val;
    __syncthreads();
  }
  if (t < NB) {
    int hv = hist[t];
    int lstart = val - hv;
    lcur[t] = lstart;
    int prior = hv ? atomicAdd(&bucket_cnt[t], hv) : 0;
    wbase[t] = t * BCAP + prior - lstart;
  }
  __syncthreads();
#pragma unroll
  for (int i = 0; i < PA_PER; ++i) {
    if (pk[i] != 0xffffffffu) {
      int b = pk[i] >> 23;
      int pos = atomicAdd(&lcur[b], 1);
      sp[pos] = pk[i];
    }
  }
  __syncthreads();
  for (int i = t; i < PA_CHUNK; i += PA_T) {
    unsigned p = sp[i];
    int b = p >> 23;
    int slot = wbase[b] + i;
    if (slot < (b + 1) * BCAP) ebuf[slot] = p;  // capacity guard (never fires)
  }
}

// ---------------------------------------------------------------------------
// Pass B: per bucket, LDS histogram over its 128 dsts -> scan -> rowptr/deg
// -> LDS-cursor scatter of u16 src ids into the bucket's csr window.
// ---------------------------------------------------------------------------
__global__ __launch_bounds__(512) void k_csr(const int* __restrict__ bucket_cnt,
                                             const unsigned* __restrict__ ebuf,
                                             int* __restrict__ rowptr,
                                             int* __restrict__ deg,
                                             unsigned short* __restrict__ csr) {
  __shared__ int hist[PART];
  __shared__ int pfx[PART];
  __shared__ int cur[PART];
  int b = blockIdx.x, t = threadIdx.x;
  int cnt = bucket_cnt[b];
  if (cnt > BCAP) cnt = BCAP;
  int ebase = b * BCAP;
  if (t < PART) hist[t] = 0;
  __syncthreads();
  for (int e = t; e < cnt; e += 512)
    atomicAdd(&hist[(ebuf[ebase + e] >> 16) & 127], 1);
  __syncthreads();
  if (t < PART) pfx[t] = hist[t];
  __syncthreads();
  for (int d = 1; d < PART; d <<= 1) {
    int v = 0;
    if (t < PART) { v = pfx[t]; if (t >= d) v += pfx[t - d]; }
    __syncthreads();
    if (t < PART) pfx[t] = v;
    __syncthreads();
  }
  if (t < PART) {
    int excl = pfx[t] - hist[t];
    cur[t] = ebase + excl;
    int dst = b * PART + t;
    if (dst < N_NODES) {
      rowptr[dst] = ebase + excl;
      deg[dst] = hist[t];
    }
  }
  __syncthreads();
  for (int e = t; e < cnt; e += 512) {
    unsigned p = ebuf[ebase + e];
    int pos = atomicAdd(&cur[(p >> 16) & 127], 1);
    csr[pos] = (unsigned short)(p & 0xffffu);
  }
}

// ---------------------------------------------------------------------------
// Pull-aggregate, 4-edges-per-load layout: lane = (group g=lane>>4, slice
// m=lane&15). Lane gathers a 16 B dwordx4 slice (channels 8m..8m+7, head
// m>>1) of edge e0+g -> one wave covers 4 edges per load instruction, expf
// redundancy 2x (was 8x). 2-deep unroll = 8 edges in flight. Cross-group
// butterfly (xor 16, 32) reduces acc+dsum; group 0 writes out.
// ---------------------------------------------------------------------------
__global__ __launch_bounds__(256) void k_aggr(const int* __restrict__ rowptr,
                                              const int* __restrict__ deg,
                                              const unsigned short* __restrict__ csr,
                                              const __bf16* __restrict__ embb,
                                              const float* __restrict__ leftp,
                                              const float* __restrict__ rightp,
                                              const float* __restrict__ bias,
                                              float* __restrict__ out) {
  int dst = blockIdx.x * 4 + (threadIdx.x >> 6);
  int lane = threadIdx.x & 63;
  int g = lane >> 4;        // edge group 0..3
  int m = lane & 15;        // 16 B slice: channels 8m..8m+7
  int h = m >> 1;           // head of this slice
  int beg = __builtin_amdgcn_readfirstlane(rowptr[dst]);
  int cnt = __builtin_amdgcn_readfirstlane(deg[dst]);
  float r = rightp[dst * HEADS + h];
  float acc[8] = {0.f, 0.f, 0.f, 0.f, 0.f, 0.f, 0.f, 0.f};
  float dsum = 0.f;
  for (int e0 = 0; e0 < cnt; e0 += 8) {
    int i0 = e0 + g, i1 = e0 + 4 + g;
    bool a0 = i0 < cnt, a1 = i1 < cnt;
    int s0 = csr[beg + (a0 ? i0 : 0)];
    int s1 = csr[beg + (a1 ? i1 : 0)];
    uint4 u0 = ((const uint4*)(embb + (size_t)s0 * CH))[m];
    uint4 u1 = ((const uint4*)(embb + (size_t)s1 * CH))[m];
    float l0 = leftp[s0 * HEADS + h];
    float l1 = leftp[s1 * HEADS + h];
    float x0 = l0 + r;
    x0 = (x0 >= 0.f) ? x0 : 0.2f * x0;
    float w0 = a0 ? __expf(x0) : 0.f;
    float x1 = l1 + r;
    x1 = (x1 >= 0.f) ? x1 : 0.2f * x1;
    float w1 = a1 ? __expf(x1) : 0.f;
    dsum += w0 + w1;
    acc[0] += w0 * bf_lo(u0.x) + w1 * bf_lo(u1.x);
    acc[1] += w0 * bf_hi(u0.x) + w1 * bf_hi(u1.x);
    acc[2] += w0 * bf_lo(u0.y) + w1 * bf_lo(u1.y);
    acc[3] += w0 * bf_hi(u0.y) + w1 * bf_hi(u1.y);
    acc[4] += w0 * bf_lo(u0.z) + w1 * bf_lo(u1.z);
    acc[5] += w0 * bf_hi(u0.z) + w1 * bf_hi(u1.z);
    acc[6] += w0 * bf_lo(u0.w) + w1 * bf_lo(u1.w);
    acc[7] += w0 * bf_hi(u0.w) + w1 * bf_hi(u1.w);
  }
  // reduce over the 4 edge groups (lane bits 4,5); m (channels/head) preserved
#pragma unroll
  for (int mask = 16; mask <= 32; mask <<= 1) {
    dsum += __shfl_xor(dsum, mask);
#pragma unroll
    for (int j = 0; j < 8; ++j) acc[j] += __shfl_xor(acc[j], mask);
  }
  if (g == 0) {
    float inv = (dsum > 0.f) ? 1.0f / dsum : 0.f;
    float4 b0 = ((const float4*)bias)[2 * m];
    float4 b1 = ((const float4*)bias)[2 * m + 1];
    float4 o0 = {acc[0] * inv + b0.x, acc[1] * inv + b0.y,
                 acc[2] * inv + b0.z, acc[3] * inv + b0.w};
    float4 o1 = {acc[4] * inv + b1.x, acc[5] * inv + b1.y,
                 acc[6] * inv + b1.z, acc[7] * inv + b1.w};
    ((float4*)(out + (size_t)dst * CH))[2 * m] = o0;
    ((float4*)(out + (size_t)dst * CH))[2 * m + 1] = o1;
  }
}

extern "C" void kernel_launch(void* const* d_in, const int* in_sizes, int n_in,
                              void* d_out, int out_size, void* d_ws, size_t ws_size,
                              hipStream_t stream) {
  const float* X = (const float*)d_in[0];
  const int* ei = (const int*)d_in[1];
  const float* W = (const float*)d_in[2];
  const float* al = (const float*)d_in[3];
  const float* ar = (const float*)d_in[4];
  const float* bias = (const float*)d_in[5];
  float* out = (float*)d_out;

  // workspace layout (~28.6 MB); embb offset is 16 B-aligned for uint4 loads
  unsigned* ebuf = (unsigned*)d_ws;                       // NB*BCAP u32 (8.0 MB)
  unsigned short* csr = (unsigned short*)(ebuf + (size_t)NB * BCAP);  // NB*BCAP u16 (4.0 MB)
  int* rowptr = (int*)(csr + (size_t)NB * BCAP);          // N int
  int* deg = rowptr + N_NODES;                            // N int
  int* bucket_cnt = deg + N_NODES;                        // NB int (pad 400)
  float* leftp = (float*)(bucket_cnt + 400);              // N*8 f32
  float* rightp = leftp + (size_t)N_NODES * HEADS;        // N*8 f32
  __bf16* embb = (__bf16*)(rightp + (size_t)N_NODES * HEADS);  // N*128 bf16 (12.8 MB)
  __bf16* Whi = embb + (size_t)N_NODES * CH;              // 16K bf16
  __bf16* Wlo = Whi + CH * CH;                            // 16K bf16

  hipMemsetAsync(bucket_cnt, 0, NB * sizeof(int), stream);

  k_splitw<<<(CH * CH / 4 + 255) / 256, 256, 0, stream>>>(W, Whi, Wlo, CH * CH / 4);
  k_emb<<<N_NODES / 16, 64, 0, stream>>>(X, Whi, Wlo, al, ar, embb, leftp, rightp);
  k_bucket<<<PA_BLOCKS, PA_T, 0, stream>>>(ei, bucket_cnt, ebuf);
  k_csr<<<NB, 512, 0, stream>>>(bucket_cnt, ebuf, rowptr, deg, csr);
  k_aggr<<<N_NODES / 4, 256, 0, stream>>>(rowptr, deg, csr, embb, leftp, rightp, bias, out);
}

// Round 7
// 214.999 us; speedup vs baseline: 1.3595x; 1.0916x over previous
//
#include <hip/hip_runtime.h>
#include <hip/hip_bf16.h>

#define N_NODES 50000
#define N_EDGES 1600000
#define HEADS 8
#define HFD 16
#define CH 128      // channels

// bucketing: bucket = dst>>7 (128 dst nodes per bucket)
#define PART 128
#define NB 391              // ceil(50000/128)
#define BCAP 5120           // edge capacity per bucket (mean 4096, +16 sigma)
#define PA_T 512
#define PA_CHUNK 3200       // edges per pass-A block
#define PA_PER 7            // 512*7 = 3584 >= 3200
#define PA_BLOCKS 500       // 500*3200 = 1.6M

typedef __bf16 bf16x8 __attribute__((ext_vector_type(8)));
typedef __bf16 bf16x4 __attribute__((ext_vector_type(4)));
typedef float f32x4 __attribute__((ext_vector_type(4)));

__device__ __forceinline__ float bf_lo(unsigned u) { return __uint_as_float(u << 16); }
__device__ __forceinline__ float bf_hi(unsigned u) { return __uint_as_float(u & 0xffff0000u); }

// ---------------------------------------------------------------------------
// Split f32 W -> bf16 hi/lo pair (x ~= hi+lo); also zeroes bucket_cnt
// (memset dispatch folded in; this kernel runs before k_bucket).
// ---------------------------------------------------------------------------
__global__ __launch_bounds__(256) void k_splitw(const float* __restrict__ x,
                                                __bf16* __restrict__ hi,
                                                __bf16* __restrict__ lo,
                                                int n4,
                                                int* __restrict__ bucket_cnt) {
  int t = blockIdx.x * 256 + threadIdx.x;
  if (t < NB) bucket_cnt[t] = 0;
  if (t >= n4) return;
  f32x4 v = ((const f32x4*)x)[t];
  bf16x4 h, l;
#pragma unroll
  for (int i = 0; i < 4; ++i) {
    __bf16 hb = (__bf16)v[i];
    h[i] = hb;
    l[i] = (__bf16)(v[i] - (float)hb);
  }
  ((bf16x4*)hi)[t] = h;
  ((bf16x4*)lo)[t] = l;
}

// ---------------------------------------------------------------------------
// emb = X @ W^T via split-bf16 MFMA. One wave per 16-node row block; A-frags
// loaded+split once, reused across all 8 head tiles. Fused logits via
// shuffle-reduce; bf16 emb out. C/D: col=lane&15, row=(lane>>4)*4+r.
// ---------------------------------------------------------------------------
__global__ __launch_bounds__(64) void k_emb(const float* __restrict__ X,
                                            const __bf16* __restrict__ Whi,
                                            const __bf16* __restrict__ Wlo,
                                            const float* __restrict__ aL,
                                            const float* __restrict__ aR,
                                            __bf16* __restrict__ embb,
                                            float* __restrict__ leftp,
                                            float* __restrict__ rightp) {
  int ntile = blockIdx.x;
  int lane = threadIdx.x;
  int c = lane & 15, quad = lane >> 4;
  const float* xp = X + (size_t)(ntile * 16 + c) * CH + quad * 8;
  bf16x8 xh[4], xl[4];
#pragma unroll
  for (int ks = 0; ks < 4; ++ks) {
    float4 x0 = *(const float4*)(xp + ks * 32);
    float4 x1 = *(const float4*)(xp + ks * 32 + 4);
    float xv[8] = {x0.x, x0.y, x0.z, x0.w, x1.x, x1.y, x1.z, x1.w};
#pragma unroll
    for (int j = 0; j < 8; ++j) {
      __bf16 hb = (__bf16)xv[j];
      xh[ks][j] = hb;
      xl[ks][j] = (__bf16)(xv[j] - (float)hb);
    }
  }
#pragma unroll
  for (int h = 0; h < HEADS; ++h) {
    const __bf16* wp = Whi + (size_t)(h * 16 + c) * CH + quad * 8;
    const __bf16* wlp = Wlo + (size_t)(h * 16 + c) * CH + quad * 8;
    f32x4 acc = {0.f, 0.f, 0.f, 0.f};
#pragma unroll
    for (int ks = 0; ks < 4; ++ks) {
      bf16x8 wh = *(const bf16x8*)(wp + ks * 32);
      bf16x8 wl = *(const bf16x8*)(wlp + ks * 32);
      acc = __builtin_amdgcn_mfma_f32_16x16x32_bf16(xl[ks], wh, acc, 0, 0, 0);
      acc = __builtin_amdgcn_mfma_f32_16x16x32_bf16(xh[ks], wl, acc, 0, 0, 0);
      acc = __builtin_amdgcn_mfma_f32_16x16x32_bf16(xh[ks], wh, acc, 0, 0, 0);
    }
    float aLv = aL[c * HEADS + h];
    float aRv = aR[c * HEADS + h];
#pragma unroll
    for (int r = 0; r < 4; ++r) {
      int node = ntile * 16 + quad * 4 + r;
      float v = acc[r];
      embb[(size_t)node * CH + h * HFD + c] = (__bf16)v;
      float sl = v * aLv, sr = v * aRv;
#pragma unroll
      for (int mm = 1; mm < 16; mm <<= 1) {
        sl += __shfl_xor(sl, mm);
        sr += __shfl_xor(sr, mm);
      }
      if (c == 0) {
        leftp[node * HEADS + h] = sl;
        rightp[node * HEADS + h] = sr;
      }
    }
  }
}

// ---------------------------------------------------------------------------
// Pass A: bucket edges by dst>>7. Packed 4 B edges held in REGISTERS through
// hist -> scan -> LDS bucket-sort (single ei read), then run-contiguous
// global writes into per-bucket windows (one reserving atomic per
// block,bucket pair).  p = (bucket:9 <<23) | (dstloc:7 <<16) | (src:16).
// 500 blocks x 3200 edges: ~20 KB LDS -> ~4 blocks/CU (was 1 at 6400).
// ---------------------------------------------------------------------------
__global__ __launch_bounds__(PA_T) void k_bucket(const int* __restrict__ ei,
                                                 int* __restrict__ bucket_cnt,
                                                 unsigned* __restrict__ ebuf) {
  __shared__ unsigned sp[PA_CHUNK];   // 12.8 KB sorted edges
  __shared__ int hist[NB];
  __shared__ int lcur[NB];
  __shared__ int wbase[NB];
  __shared__ int scn[PA_T];
  int t = threadIdx.x;
  int base = blockIdx.x * PA_CHUNK;
  for (int i = t; i < NB; i += PA_T) hist[i] = 0;
  __syncthreads();
  unsigned pk[PA_PER];
#pragma unroll
  for (int i = 0; i < PA_PER; ++i) {
    int e = t + i * PA_T;
    pk[i] = 0xffffffffu;
    if (e < PA_CHUNK) {
      int src = ei[base + e];
      int dst = ei[N_EDGES + base + e];
      pk[i] = ((unsigned)(dst >> 7) << 23) | ((unsigned)(dst & 127) << 16) |
              (unsigned)src;
      atomicAdd(&hist[dst >> 7], 1);
    }
  }
  __syncthreads();
  // inclusive scan over NB buckets (padded Hillis-Steele over 512)
  scn[t] = (t < NB) ? hist[t] : 0;
  __syncthreads();
  int val = scn[t];
  for (int d = 1; d < PA_T; d <<= 1) {
    int o = (t >= d) ? scn[t - d] : 0;
    __syncthreads();
    val += o;
    scn[t] = val;
    __syncthreads();
  }
  if (t < NB) {
    int hv = hist[t];
    int lstart = val - hv;
    lcur[t] = lstart;
    int prior = hv ? atomicAdd(&bucket_cnt[t], hv) : 0;
    wbase[t] = t * BCAP + prior - lstart;
  }
  __syncthreads();
#pragma unroll
  for (int i = 0; i < PA_PER; ++i) {
    if (pk[i] != 0xffffffffu) {
      int b = pk[i] >> 23;
      int pos = atomicAdd(&lcur[b], 1);
      sp[pos] = pk[i];
    }
  }
  __syncthreads();
  for (int i = t; i < PA_CHUNK; i += PA_T) {
    unsigned p = sp[i];
    int b = p >> 23;
    int slot = wbase[b] + i;
    if (slot < (b + 1) * BCAP) ebuf[slot] = p;  // capacity guard (never fires)
  }
}

// ---------------------------------------------------------------------------
// Fused CSR-sort + pull-aggregate. One block per HALF-bucket (782 blocks,
// 512 threads, ~32 KB LDS -> 4 blocks/CU, all blocks resident in one cohort).
// Block stages its bucket's edge window in LDS, hist+scan+scatter sorts by
// dstloc (both halves redo this cheap sort), then each of 8 waves aggregates
// 8 dsts: lane = (group g=lane>>4 -> edge, slice m=lane&15 -> 16 B of the
// 256 B emb row), 2-deep unroll = 8 edges in flight, butterfly xor16/32
// reduce, group 0 writes out = acc/dsum + bias.
// ---------------------------------------------------------------------------
__global__ __launch_bounds__(512) void k_aggr(const int* __restrict__ bucket_cnt,
                                              const unsigned* __restrict__ ebuf,
                                              const __bf16* __restrict__ embb,
                                              const float* __restrict__ leftp,
                                              const float* __restrict__ rightp,
                                              const float* __restrict__ bias,
                                              float* __restrict__ out) {
  __shared__ unsigned sp[BCAP];        // 20.5 KB raw window copy
  __shared__ unsigned short su[BCAP];  // 10.2 KB dstloc-sorted src ids
  __shared__ int hist[PART];
  __shared__ int pfx[PART];
  __shared__ int cur[PART];
  int b = blockIdx.x >> 1;
  int half = blockIdx.x & 1;
  int t = threadIdx.x;
  int cnt = bucket_cnt[b];
  if (cnt > BCAP) cnt = BCAP;
  int ebase = b * BCAP;
  if (t < PART) hist[t] = 0;
  __syncthreads();
  for (int e = t; e < cnt; e += 512) {
    unsigned p = ebuf[ebase + e];
    sp[e] = p;
    atomicAdd(&hist[(p >> 16) & 127], 1);
  }
  __syncthreads();
  if (t < PART) pfx[t] = hist[t];
  __syncthreads();
  for (int d = 1; d < PART; d <<= 1) {
    int v = 0;
    if (t < PART) { v = pfx[t]; if (t >= d) v += pfx[t - d]; }
    __syncthreads();
    if (t < PART) pfx[t] = v;
    __syncthreads();
  }
  if (t < PART) {
    int excl = pfx[t] - hist[t];
    pfx[t] = excl;
    cur[t] = excl;
  }
  __syncthreads();
  for (int e = t; e < cnt; e += 512) {
    unsigned p = sp[e];
    int pos = atomicAdd(&cur[(p >> 16) & 127], 1);
    su[pos] = (unsigned short)(p & 0xffffu);
  }
  __syncthreads();

  int wv = t >> 6;
  int lane = t & 63;
  int g = lane >> 4;        // edge group 0..3
  int m = lane & 15;        // 16 B slice: channels 8m..8m+7
  int h = m >> 1;           // head of this slice
#pragma unroll
  for (int k = 0; k < 8; ++k) {
    int dl = half * 64 + wv * 8 + k;
    int dst = b * PART + dl;
    bool valid = dst < N_NODES;
    int beg = pfx[dl];
    int cd = hist[dl];
    float r = valid ? rightp[dst * HEADS + h] : 0.f;
    float acc[8] = {0.f, 0.f, 0.f, 0.f, 0.f, 0.f, 0.f, 0.f};
    float dsum = 0.f;
    for (int e0 = 0; e0 < cd; e0 += 8) {
      int i0 = e0 + g, i1 = e0 + 4 + g;
      bool a0 = i0 < cd, a1 = i1 < cd;
      int s0 = su[beg + (a0 ? i0 : 0)];
      int s1 = su[beg + (a1 ? i1 : 0)];
      uint4 u0 = ((const uint4*)(embb + (size_t)s0 * CH))[m];
      uint4 u1 = ((const uint4*)(embb + (size_t)s1 * CH))[m];
      float l0 = leftp[s0 * HEADS + h];
      float l1 = leftp[s1 * HEADS + h];
      float x0 = l0 + r;
      x0 = (x0 >= 0.f) ? x0 : 0.2f * x0;
      float w0 = a0 ? __expf(x0) : 0.f;
      float x1 = l1 + r;
      x1 = (x1 >= 0.f) ? x1 : 0.2f * x1;
      float w1 = a1 ? __expf(x1) : 0.f;
      dsum += w0 + w1;
      acc[0] += w0 * bf_lo(u0.x) + w1 * bf_lo(u1.x);
      acc[1] += w0 * bf_hi(u0.x) + w1 * bf_hi(u1.x);
      acc[2] += w0 * bf_lo(u0.y) + w1 * bf_lo(u1.y);
      acc[3] += w0 * bf_hi(u0.y) + w1 * bf_hi(u1.y);
      acc[4] += w0 * bf_lo(u0.z) + w1 * bf_lo(u1.z);
      acc[5] += w0 * bf_hi(u0.z) + w1 * bf_hi(u1.z);
      acc[6] += w0 * bf_lo(u0.w) + w1 * bf_lo(u1.w);
      acc[7] += w0 * bf_hi(u0.w) + w1 * bf_hi(u1.w);
    }
    // reduce over the 4 edge groups (lane bits 4,5)
#pragma unroll
    for (int mask = 16; mask <= 32; mask <<= 1) {
      dsum += __shfl_xor(dsum, mask);
#pragma unroll
      for (int j = 0; j < 8; ++j) acc[j] += __shfl_xor(acc[j], mask);
    }
    if (g == 0 && valid) {
      float inv = (dsum > 0.f) ? 1.0f / dsum : 0.f;
      float4 b0 = ((const float4*)bias)[2 * m];
      float4 b1 = ((const float4*)bias)[2 * m + 1];
      float4 o0 = {acc[0] * inv + b0.x, acc[1] * inv + b0.y,
                   acc[2] * inv + b0.z, acc[3] * inv + b0.w};
      float4 o1 = {acc[4] * inv + b1.x, acc[5] * inv + b1.y,
                   acc[6] * inv + b1.z, acc[7] * inv + b1.w};
      ((float4*)(out + (size_t)dst * CH))[2 * m] = o0;
      ((float4*)(out + (size_t)dst * CH))[2 * m + 1] = o1;
    }
  }
}

extern "C" void kernel_launch(void* const* d_in, const int* in_sizes, int n_in,
                              void* d_out, int out_size, void* d_ws, size_t ws_size,
                              hipStream_t stream) {
  const float* X = (const float*)d_in[0];
  const int* ei = (const int*)d_in[1];
  const float* W = (const float*)d_in[2];
  const float* al = (const float*)d_in[3];
  const float* ar = (const float*)d_in[4];
  const float* bias = (const float*)d_in[5];
  float* out = (float*)d_out;

  // workspace layout (~22.5 MB); all segments 16 B-aligned
  unsigned* ebuf = (unsigned*)d_ws;                       // NB*BCAP u32 (8.0 MB)
  __bf16* embb = (__bf16*)(ebuf + (size_t)NB * BCAP);     // N*128 bf16 (12.8 MB)
  __bf16* Whi = embb + (size_t)N_NODES * CH;              // 16K bf16
  __bf16* Wlo = Whi + CH * CH;                            // 16K bf16
  float* leftp = (float*)(Wlo + CH * CH);                 // N*8 f32
  float* rightp = leftp + (size_t)N_NODES * HEADS;        // N*8 f32
  int* bucket_cnt = (int*)(rightp + (size_t)N_NODES * HEADS);  // NB int

  k_splitw<<<(CH * CH / 4 + 255) / 256, 256, 0, stream>>>(W, Whi, Wlo, CH * CH / 4,
                                                          bucket_cnt);
  k_bucket<<<PA_BLOCKS, PA_T, 0, stream>>>(ei, bucket_cnt, ebuf);
  k_emb<<<N_NODES / 16, 64, 0, stream>>>(X, Whi, Wlo, al, ar, embb, leftp, rightp);
  k_aggr<<<NB * 2, 512, 0, stream>>>(bucket_cnt, ebuf, embb, leftp, rightp, bias, out);
}

// Round 8
// 211.389 us; speedup vs baseline: 1.3828x; 1.0171x over previous
//
#include <hip/hip_runtime.h>
#include <hip/hip_bf16.h>

#define N_NODES 50000
#define N_EDGES 1600000
#define HEADS 8
#define HFD 16
#define CH 128      // channels

// bucketing: bucket = dst>>7 (128 dst nodes per bucket)
#define PART 128
#define NB 391              // ceil(50000/128)
#define BCAP 5120           // edge capacity per bucket (mean 4096, +16 sigma)
#define PA_T 512
#define PA_CHUNK 3200       // edges per pass-A block
#define PA_PER 7            // 512*7 = 3584 >= 3200
#define PA_BLOCKS 500       // 500*3200 = 1.6M

typedef __bf16 bf16x8 __attribute__((ext_vector_type(8)));
typedef __bf16 bf16x4 __attribute__((ext_vector_type(4)));
typedef float f32x4 __attribute__((ext_vector_type(4)));

__device__ __forceinline__ float bf_lo(unsigned u) { return __uint_as_float(u << 16); }
__device__ __forceinline__ float bf_hi(unsigned u) { return __uint_as_float(u & 0xffff0000u); }

// ---------------------------------------------------------------------------
// Prep kernel: (a) split W f32 -> bf16 hi/lo; (b) build the 16x128 effective
// logit tile Veff (rows 0..7 = aL^T W-blocks per head, rows 8..15 = aR^T)
// and split it to bf16 hi/lo; (c) zero bucket_cnt. 4096 threads.
//   vl[h][k] = sum_c aL[c,h] * W[h*16+c][k]   (left = emb . aL per head)
// ---------------------------------------------------------------------------
__global__ __launch_bounds__(256) void k_splitw(const float* __restrict__ W,
                                                const float* __restrict__ aL,
                                                const float* __restrict__ aR,
                                                __bf16* __restrict__ Whi,
                                                __bf16* __restrict__ Wlo,
                                                __bf16* __restrict__ Vhi,
                                                __bf16* __restrict__ Vlo,
                                                int* __restrict__ bucket_cnt) {
  int t = blockIdx.x * 256 + threadIdx.x;
  if (t < NB) bucket_cnt[t] = 0;
  if (t < CH * CH / 4) {
    f32x4 v = ((const f32x4*)W)[t];
    bf16x4 h, l;
#pragma unroll
    for (int i = 0; i < 4; ++i) {
      __bf16 hb = (__bf16)v[i];
      h[i] = hb;
      l[i] = (__bf16)(v[i] - (float)hb);
    }
    ((bf16x4*)Whi)[t] = h;
    ((bf16x4*)Wlo)[t] = l;
  }
  if (t < 16 * CH) {
    int j = t >> 7;          // 0..15: logit row (0..7 left, 8..15 right)
    int k = t & 127;         // input channel
    int h = j & 7;
    const float* a = (j < 8) ? aL : aR;
    float v = 0.f;
#pragma unroll
    for (int c = 0; c < HFD; ++c) v += W[(h * HFD + c) * CH + k] * a[c * HEADS + h];
    __bf16 hb = (__bf16)v;
    Vhi[t] = hb;
    Vlo[t] = (__bf16)(v - (float)hb);
  }
}

// ---------------------------------------------------------------------------
// emb = X @ W^T via split-bf16 MFMA. One wave per 16-node row block; A-frags
// loaded+split once, reused across 8 head tiles + 1 logit tile (Veff).
// Logits come out of a 4th MFMA accumulator: D[node, j] with j<8 -> left
// head j, j>=8 -> right head j-8; direct coalesced writes (no shuffles).
// C/D: col=lane&15, row=(lane>>4)*4+r (HW-verified, passed r2-r7).
// ---------------------------------------------------------------------------
__global__ __launch_bounds__(64) void k_emb(const float* __restrict__ X,
                                            const __bf16* __restrict__ Whi,
                                            const __bf16* __restrict__ Wlo,
                                            const __bf16* __restrict__ Vhi,
                                            const __bf16* __restrict__ Vlo,
                                            __bf16* __restrict__ embb,
                                            float* __restrict__ leftp,
                                            float* __restrict__ rightp) {
  int ntile = blockIdx.x;
  int lane = threadIdx.x;
  int c = lane & 15, quad = lane >> 4;
  const float* xp = X + (size_t)(ntile * 16 + c) * CH + quad * 8;
  bf16x8 xh[4], xl[4];
#pragma unroll
  for (int ks = 0; ks < 4; ++ks) {
    float4 x0 = *(const float4*)(xp + ks * 32);
    float4 x1 = *(const float4*)(xp + ks * 32 + 4);
    float xv[8] = {x0.x, x0.y, x0.z, x0.w, x1.x, x1.y, x1.z, x1.w};
#pragma unroll
    for (int j = 0; j < 8; ++j) {
      __bf16 hb = (__bf16)xv[j];
      xh[ks][j] = hb;
      xl[ks][j] = (__bf16)(xv[j] - (float)hb);
    }
  }
  // 8 head tiles -> bf16 emb
#pragma unroll
  for (int h = 0; h < HEADS; ++h) {
    const __bf16* wp = Whi + (size_t)(h * 16 + c) * CH + quad * 8;
    const __bf16* wlp = Wlo + (size_t)(h * 16 + c) * CH + quad * 8;
    f32x4 acc = {0.f, 0.f, 0.f, 0.f};
#pragma unroll
    for (int ks = 0; ks < 4; ++ks) {
      bf16x8 wh = *(const bf16x8*)(wp + ks * 32);
      bf16x8 wl = *(const bf16x8*)(wlp + ks * 32);
      acc = __builtin_amdgcn_mfma_f32_16x16x32_bf16(xl[ks], wh, acc, 0, 0, 0);
      acc = __builtin_amdgcn_mfma_f32_16x16x32_bf16(xh[ks], wl, acc, 0, 0, 0);
      acc = __builtin_amdgcn_mfma_f32_16x16x32_bf16(xh[ks], wh, acc, 0, 0, 0);
    }
#pragma unroll
    for (int r = 0; r < 4; ++r) {
      int node = ntile * 16 + quad * 4 + r;
      embb[(size_t)node * CH + h * HFD + c] = (__bf16)acc[r];
    }
  }
  // logit tile
  {
    const __bf16* vp = Vhi + (size_t)c * CH + quad * 8;
    const __bf16* vlp = Vlo + (size_t)c * CH + quad * 8;
    f32x4 acc = {0.f, 0.f, 0.f, 0.f};
#pragma unroll
    for (int ks = 0; ks < 4; ++ks) {
      bf16x8 vh = *(const bf16x8*)(vp + ks * 32);
      bf16x8 vl = *(const bf16x8*)(vlp + ks * 32);
      acc = __builtin_amdgcn_mfma_f32_16x16x32_bf16(xl[ks], vh, acc, 0, 0, 0);
      acc = __builtin_amdgcn_mfma_f32_16x16x32_bf16(xh[ks], vl, acc, 0, 0, 0);
      acc = __builtin_amdgcn_mfma_f32_16x16x32_bf16(xh[ks], vh, acc, 0, 0, 0);
    }
#pragma unroll
    for (int r = 0; r < 4; ++r) {
      int node = ntile * 16 + quad * 4 + r;
      if (c < 8) leftp[node * HEADS + c] = acc[r];
      else rightp[node * HEADS + (c - 8)] = acc[r];
    }
  }
}

// ---------------------------------------------------------------------------
// Pass A: bucket edges by dst>>7. Packed 4 B edges held in REGISTERS through
// hist -> scan -> LDS bucket-sort (single ei read), then run-contiguous
// global writes into per-bucket windows (one reserving atomic per
// block,bucket pair).  p = (bucket:9 <<23) | (dstloc:7 <<16) | (src:16).
// ---------------------------------------------------------------------------
__global__ __launch_bounds__(PA_T) void k_bucket(const int* __restrict__ ei,
                                                 int* __restrict__ bucket_cnt,
                                                 unsigned* __restrict__ ebuf) {
  __shared__ unsigned sp[PA_CHUNK];   // 12.8 KB sorted edges
  __shared__ int hist[NB];
  __shared__ int lcur[NB];
  __shared__ int wbase[NB];
  __shared__ int scn[PA_T];
  int t = threadIdx.x;
  int base = blockIdx.x * PA_CHUNK;
  for (int i = t; i < NB; i += PA_T) hist[i] = 0;
  __syncthreads();
  unsigned pk[PA_PER];
#pragma unroll
  for (int i = 0; i < PA_PER; ++i) {
    int e = t + i * PA_T;
    pk[i] = 0xffffffffu;
    if (e < PA_CHUNK) {
      int src = ei[base + e];
      int dst = ei[N_EDGES + base + e];
      pk[i] = ((unsigned)(dst >> 7) << 23) | ((unsigned)(dst & 127) << 16) |
              (unsigned)src;
      atomicAdd(&hist[dst >> 7], 1);
    }
  }
  __syncthreads();
  // inclusive scan over NB buckets (padded Hillis-Steele over 512)
  scn[t] = (t < NB) ? hist[t] : 0;
  __syncthreads();
  int val = scn[t];
  for (int d = 1; d < PA_T; d <<= 1) {
    int o = (t >= d) ? scn[t - d] : 0;
    __syncthreads();
    val += o;
    scn[t] = val;
    __syncthreads();
  }
  if (t < NB) {
    int hv = hist[t];
    int lstart = val - hv;
    lcur[t] = lstart;
    int prior = hv ? atomicAdd(&bucket_cnt[t], hv) : 0;
    wbase[t] = t * BCAP + prior - lstart;
  }
  __syncthreads();
#pragma unroll
  for (int i = 0; i < PA_PER; ++i) {
    if (pk[i] != 0xffffffffu) {
      int b = pk[i] >> 23;
      int pos = atomicAdd(&lcur[b], 1);
      sp[pos] = pk[i];
    }
  }
  __syncthreads();
  for (int i = t; i < PA_CHUNK; i += PA_T) {
    unsigned p = sp[i];
    int b = p >> 23;
    int slot = wbase[b] + i;
    if (slot < (b + 1) * BCAP) ebuf[slot] = p;  // capacity guard (never fires)
  }
}

// ---------------------------------------------------------------------------
// Fused CSR-sort + pull-aggregate. One block per HALF-bucket (782 blocks,
// 512 threads). LDS slimmed to ~11.8 KB (no staging copy; ebuf read twice:
// hist pass + scatter pass) -> 4 blocks/CU resident (was 2 at 32 KB).
// Each of 8 waves aggregates 8 dsts: lane = (group g=lane>>4 -> edge, slice
// m=lane&15 -> 16 B of the 256 B emb row), 2-deep unroll = 8 edges in
// flight, butterfly xor16/32 reduce, group 0 writes out = acc/dsum + bias.
// ---------------------------------------------------------------------------
__global__ __launch_bounds__(512) void k_aggr(const int* __restrict__ bucket_cnt,
                                              const unsigned* __restrict__ ebuf,
                                              const __bf16* __restrict__ embb,
                                              const float* __restrict__ leftp,
                                              const float* __restrict__ rightp,
                                              const float* __restrict__ bias,
                                              float* __restrict__ out) {
  __shared__ unsigned short su[BCAP];  // 10.2 KB dstloc-sorted src ids
  __shared__ int hist[PART];
  __shared__ int pfx[PART];
  __shared__ int cur[PART];
  int b = blockIdx.x >> 1;
  int half = blockIdx.x & 1;
  int t = threadIdx.x;
  int cnt = bucket_cnt[b];
  if (cnt > BCAP) cnt = BCAP;
  int ebase = b * BCAP;
  if (t < PART) hist[t] = 0;
  __syncthreads();
  for (int e = t; e < cnt; e += 512)
    atomicAdd(&hist[(ebuf[ebase + e] >> 16) & 127], 1);
  __syncthreads();
  if (t < PART) pfx[t] = hist[t];
  __syncthreads();
  for (int d = 1; d < PART; d <<= 1) {
    int v = 0;
    if (t < PART) { v = pfx[t]; if (t >= d) v += pfx[t - d]; }
    __syncthreads();
    if (t < PART) pfx[t] = v;
    __syncthreads();
  }
  if (t < PART) {
    int excl = pfx[t] - hist[t];
    pfx[t] = excl;
    cur[t] = excl;
  }
  __syncthreads();
  for (int e = t; e < cnt; e += 512) {
    unsigned p = ebuf[ebase + e];
    int pos = atomicAdd(&cur[(p >> 16) & 127], 1);
    su[pos] = (unsigned short)(p & 0xffffu);
  }
  __syncthreads();

  int wv = t >> 6;
  int lane = t & 63;
  int g = lane >> 4;        // edge group 0..3
  int m = lane & 15;        // 16 B slice: channels 8m..8m+7
  int h = m >> 1;           // head of this slice
#pragma unroll
  for (int k = 0; k < 8; ++k) {
    int dl = half * 64 + wv * 8 + k;
    int dst = b * PART + dl;
    bool valid = dst < N_NODES;
    int beg = pfx[dl];
    int cd = hist[dl];
    float r = valid ? rightp[dst * HEADS + h] : 0.f;
    float acc[8] = {0.f, 0.f, 0.f, 0.f, 0.f, 0.f, 0.f, 0.f};
    float dsum = 0.f;
    for (int e0 = 0; e0 < cd; e0 += 8) {
      int i0 = e0 + g, i1 = e0 + 4 + g;
      bool a0 = i0 < cd, a1 = i1 < cd;
      int s0 = su[beg + (a0 ? i0 : 0)];
      int s1 = su[beg + (a1 ? i1 : 0)];
      uint4 u0 = ((const uint4*)(embb + (size_t)s0 * CH))[m];
      uint4 u1 = ((const uint4*)(embb + (size_t)s1 * CH))[m];
      float l0 = leftp[s0 * HEADS + h];
      float l1 = leftp[s1 * HEADS + h];
      float x0 = l0 + r;
      x0 = (x0 >= 0.f) ? x0 : 0.2f * x0;
      float w0 = a0 ? __expf(x0) : 0.f;
      float x1 = l1 + r;
      x1 = (x1 >= 0.f) ? x1 : 0.2f * x1;
      float w1 = a1 ? __expf(x1) : 0.f;
      dsum += w0 + w1;
      acc[0] += w0 * bf_lo(u0.x) + w1 * bf_lo(u1.x);
      acc[1] += w0 * bf_hi(u0.x) + w1 * bf_hi(u1.x);
      acc[2] += w0 * bf_lo(u0.y) + w1 * bf_lo(u1.y);
      acc[3] += w0 * bf_hi(u0.y) + w1 * bf_hi(u1.y);
      acc[4] += w0 * bf_lo(u0.z) + w1 * bf_lo(u1.z);
      acc[5] += w0 * bf_hi(u0.z) + w1 * bf_hi(u1.z);
      acc[6] += w0 * bf_lo(u0.w) + w1 * bf_lo(u1.w);
      acc[7] += w0 * bf_hi(u0.w) + w1 * bf_hi(u1.w);
    }
    // reduce over the 4 edge groups (lane bits 4,5)
#pragma unroll
    for (int mask = 16; mask <= 32; mask <<= 1) {
      dsum += __shfl_xor(dsum, mask);
#pragma unroll
      for (int j = 0; j < 8; ++j) acc[j] += __shfl_xor(acc[j], mask);
    }
    if (g == 0 && valid) {
      float inv = (dsum > 0.f) ? 1.0f / dsum : 0.f;
      float4 b0 = ((const float4*)bias)[2 * m];
      float4 b1 = ((const float4*)bias)[2 * m + 1];
      float4 o0 = {acc[0] * inv + b0.x, acc[1] * inv + b0.y,
                   acc[2] * inv + b0.z, acc[3] * inv + b0.w};
      float4 o1 = {acc[4] * inv + b1.x, acc[5] * inv + b1.y,
                   acc[6] * inv + b1.z, acc[7] * inv + b1.w};
      ((float4*)(out + (size_t)dst * CH))[2 * m] = o0;
      ((float4*)(out + (size_t)dst * CH))[2 * m + 1] = o1;
    }
  }
}

extern "C" void kernel_launch(void* const* d_in, const int* in_sizes, int n_in,
                              void* d_out, int out_size, void* d_ws, size_t ws_size,
                              hipStream_t stream) {
  const float* X = (const float*)d_in[0];
  const int* ei = (const int*)d_in[1];
  const float* W = (const float*)d_in[2];
  const float* al = (const float*)d_in[3];
  const float* ar = (const float*)d_in[4];
  const float* bias = (const float*)d_in[5];
  float* out = (float*)d_out;

  // workspace layout (~22.6 MB); all segments 16 B-aligned
  unsigned* ebuf = (unsigned*)d_ws;                       // NB*BCAP u32 (8.0 MB)
  __bf16* embb = (__bf16*)(ebuf + (size_t)NB * BCAP);     // N*128 bf16 (12.8 MB)
  __bf16* Whi = embb + (size_t)N_NODES * CH;              // 16K bf16
  __bf16* Wlo = Whi + CH * CH;                            // 16K bf16
  __bf16* Vhi = Wlo + CH * CH;                            // 2K bf16
  __bf16* Vlo = Vhi + 16 * CH;                            // 2K bf16
  float* leftp = (float*)(Vlo + 16 * CH);                 // N*8 f32
  float* rightp = leftp + (size_t)N_NODES * HEADS;        // N*8 f32
  int* bucket_cnt = (int*)(rightp + (size_t)N_NODES * HEADS);  // NB int

  k_splitw<<<16, 256, 0, stream>>>(W, al, ar, Whi, Wlo, Vhi, Vlo, bucket_cnt);
  k_bucket<<<PA_BLOCKS, PA_T, 0, stream>>>(ei, bucket_cnt, ebuf);
  k_emb<<<N_NODES / 16, 64, 0, stream>>>(X, Whi, Wlo, Vhi, Vlo, embb, leftp, rightp);
  k_aggr<<<NB * 2, 512, 0, stream>>>(bucket_cnt, ebuf, embb, leftp, rightp, bias, out);
}